// Round 2
// baseline (306.290 us; speedup 1.0000x reference)
//
#include <hip/hip_runtime.h>

// nw_out [N=4, C=19, H=512, W=1024] fp32; output: 1 fp32 scalar.
#define N_IMG 4
#define C_CLS 19
#define HW    (512 * 1024)          // per-channel plane
#define NPIX  (N_IMG * HW)          // 2,097,152 pixels
#define VPIX  (NPIX / 4)            // 524,288 float4 pixel-groups
#define NBLK  (VPIX / 256)          // 2048 blocks
#define IW    0.2f

// Accumulator layout in d_ws: each of the 2*19 accumulators on its own
// 256 B slot (64 floats) so same-address atomic streams hit 38 distinct
// L2 channels instead of 3 packed cache lines. Ticket counter at the end.
#define SLOT   64
#define WS_U32 (2 * C_CLS * SLOT + 1)

typedef float f4 __attribute__((ext_vector_type(4)));

__device__ __forceinline__ float* sum_slot(float* ws, int c) { return ws + (size_t)c * SLOT; }
__device__ __forceinline__ float* cnt_slot(float* ws, int c) { return ws + (size_t)(C_CLS + c) * SLOT; }

// ---------------------------------------------------------------------------
// Kernel 1: zero the accumulator slots + ticket (ws is poisoned 0xAA per call)
// ---------------------------------------------------------------------------
__global__ void zero_ws(unsigned int* ws) {
    for (int i = threadIdx.x; i < WS_U32; i += 1024) ws[i] = 0u;
}

// ---------------------------------------------------------------------------
// Kernel 2: one pass over the input; per pixel argmax + sum(prob^2); per-class
// LDS accumulation; 38 padded global atomics per block; last block finalizes.
// ---------------------------------------------------------------------------
__global__ __launch_bounds__(256) void main_pass(const float* __restrict__ x,
                                                 float* __restrict__ ws,
                                                 unsigned int* __restrict__ ticket,
                                                 float* __restrict__ out) {
    __shared__ float s_sum[C_CLS];
    __shared__ float s_cnt[C_CLS];
    __shared__ unsigned int s_last;
    const int t = threadIdx.x;
    if (t < C_CLS) { s_sum[t] = 0.0f; s_cnt[t] = 0.0f; }
    __syncthreads();

    // vec4 pixel-group index; grid exactly covers VPIX (2048 * 256).
    const int v   = blockIdx.x * 256 + t;
    const int n   = v >> 17;                 // HW/4 = 131072 = 2^17
    const int hw4 = v & (131072 - 1);
    const float* base = x + (size_t)n * C_CLS * HW + (size_t)hw4 * 4;

    // 19 channels x 4 pixels into registers; streaming (L2-bypass hint).
    f4 val[C_CLS];
#pragma unroll
    for (int c = 0; c < C_CLS; ++c)
        val[c] = __builtin_nontemporal_load((const f4*)(base + (size_t)c * HW));

#pragma unroll
    for (int j = 0; j < 4; ++j) {
        // first-max argmax (matches jnp.argmax) + max for softmax stability
        float m = val[0][j];
        int   am = 0;
#pragma unroll
        for (int c = 1; c < C_CLS; ++c) {
            float xv = val[c][j];
            if (xv > m) { m = xv; am = c; }
        }
        float l = 0.0f, q = 0.0f;
#pragma unroll
        for (int c = 0; c < C_CLS; ++c) {
            float e = __expf(val[c][j] - m);
            l += e;
            q += e * e;
        }
        float s = q * __builtin_amdgcn_rcpf(l * l);   // sum(prob^2), ~1ulp rcp
        atomicAdd(&s_sum[am], s);
        atomicAdd(&s_cnt[am], 1.0f);                  // exact: int-valued < 2^24
    }

    __syncthreads();
    if (t < C_CLS) {
        atomicAdd(sum_slot(ws, t), s_sum[t]);
        atomicAdd(cnt_slot(ws, t), s_cnt[t]);
    }
    // __syncthreads drains vmcnt (incl. this block's global atomics) on gfx9.
    __syncthreads();
    if (t == 0) {
        __threadfence();                               // publish before ticket
        unsigned int old = atomicAdd(ticket, 1u);
        s_last = (old == NBLK - 1) ? 1u : 0u;
    }
    __syncthreads();

    if (s_last && t < 64) {                            // wave 0 of last block
        float vsum = 0.0f;
        if (t < C_CLS) {
            float cnt = __hip_atomic_load(cnt_slot(ws, t), __ATOMIC_RELAXED,
                                          __HIP_MEMORY_SCOPE_AGENT);
            float sum = __hip_atomic_load(sum_slot(ws, t), __ATOMIC_RELAXED,
                                          __HIP_MEMORY_SCOPE_AGENT);
            const float scale = powf((float)NPIX, 1.0f - IW);  // Np^0.8
            float den = fmaxf(powf(cnt, IW) * scale, 1.0f);
            vsum = sum / den;
        }
#pragma unroll
        for (int off = 32; off > 0; off >>= 1)
            vsum += __shfl_down(vsum, off);
        if (t == 0)
            out[0] = -vsum / (float)(N_IMG * C_CLS);
    }
}

extern "C" void kernel_launch(void* const* d_in, const int* in_sizes, int n_in,
                              void* d_out, int out_size, void* d_ws, size_t ws_size,
                              hipStream_t stream) {
    const float* x = (const float*)d_in[0];
    float* out = (float*)d_out;
    float* ws  = (float*)d_ws;
    unsigned int* ticket = (unsigned int*)(ws + 2 * C_CLS * SLOT);

    zero_ws<<<1, 1024, 0, stream>>>((unsigned int*)d_ws);
    main_pass<<<NBLK, 256, 0, stream>>>(x, ws, ticket, out);
}